// Round 1
// 224.688 us; speedup vs baseline: 1.0163x; 1.0163x over previous
//
#include <hip/hip_runtime.h>

#define NVOX 150000
#define BM 128
#define MTILES 1172         // ceil(150000/128)
#define SROW 150016         // 1172*128, column stride of h buffer
#define NCOL 320

typedef __attribute__((ext_vector_type(8))) short bf16x8;
typedef __attribute__((ext_vector_type(4))) float f32x4;

__device__ __forceinline__ unsigned short f2bf(float f) {
    unsigned u = __builtin_bit_cast(unsigned, f);
    u += 0x7fffu + ((u >> 16) & 1u);
    return (unsigned short)(u >> 16);
}

__device__ __forceinline__ void gld16(const void* g, void* l) {
    __builtin_amdgcn_global_load_lds(
        (const __attribute__((address_space(1))) unsigned int*)g,
        (__attribute__((address_space(3))) unsigned int*)l, 16, 0, 0);
}

// ---------------- prep: features f32 -> bf16 (+ zero row at NVOX), x8 vectorized ------
__global__ void prep_feat(const float* __restrict__ src, unsigned short* __restrict__ dst) {
    int i = blockIdx.x * 256 + threadIdx.x;   // each i handles 8 elements
    if (i < NVOX * 8) {
        const float* s = src + (size_t)i * 8;
        float4 a = *(const float4*)s;
        float4 b = *(const float4*)(s + 4);
        union { bf16x8 v; unsigned short u[8]; } r;
        r.u[0] = f2bf(a.x); r.u[1] = f2bf(a.y); r.u[2] = f2bf(a.z); r.u[3] = f2bf(a.w);
        r.u[4] = f2bf(b.x); r.u[5] = f2bf(b.y); r.u[6] = f2bf(b.z); r.u[7] = f2bf(b.w);
        *(bf16x8*)(dst + (size_t)i * 8) = r.v;
    } else if (i < NVOX * 8 + 8) {            // zero row for invalid/pad gathers
        bf16x8 z = {0, 0, 0, 0, 0, 0, 0, 0};
        *(bf16x8*)(dst + (size_t)i * 8) = z;
    }
}

// ---- prep: W3[h][kk][c][o] f32 -> Bt2 chunk-major bf16: [(h*9+kk)*8 + c16][o][c&7] ----
__global__ void prep_w3(const float* __restrict__ w3, unsigned short* __restrict__ bt,
                        float* __restrict__ stats) {
    int i = blockIdx.x * 256 + threadIdx.x;   // grid is exactly 184320 threads
    int h = i / 36864;
    int rem = i - h * 36864;
    int kk = rem >> 12;
    int c = (rem >> 6) & 63;
    int o = rem & 63;
    bt[(size_t)(((h * 9 + kk) * 8) + (c >> 3)) * 512 + o * 8 + (c & 7)] = f2bf(w3[i]);
    if (i < 2 * NCOL) stats[i] = 0.f;
}

// ---------------- gather-GEMM: double-buffered 2-phase pipeline --------------------
// BM=128, BN=64 (one head), BK=64 (one kk), 4 waves, wave tile 64x32.
// Pipeline: stage(kk+1 -> buf^1) issued BEFORE compute(kk from buf); ONE barrier/iter
// (syncthreads drains vmcnt(0) so the prefetch lands block-wide before its reads).
// LDS: sA dbuf 2x16KB @0, sB dbuf 2x8KB @32768, idx @49152 (4608B) = 53760 -> 3 blk/CU.
__global__ __launch_bounds__(256, 3)
void gemm_kernel(const unsigned short* __restrict__ featB,
                 const unsigned short* __restrict__ Bt2,
                 const int* __restrict__ nbr,
                 unsigned short* __restrict__ hbuf,
                 float* __restrict__ stats) {
    __shared__ __align__(16) char smem[53760];
    constexpr int IDX_OFF = 49152;   // 9*128 int byte-offsets
    constexpr int SRED_OFF = 32768;  // aliases dead sB region in epilogue 2

    // XCD swizzle: the 5 head-blocks of one mtile share bid%8 -> same XCD (A L2 reuse)
    int bid = blockIdx.x;
    int r = bid & 7, q = bid >> 3;
    int ntile = q % 5;
    int mtile = (q / 5) * 8 + r;
    if (mtile >= MTILES) return;
    int m0 = mtile * BM;
    int n0 = ntile * 64;

    int tid = threadIdx.x;
    int w = tid >> 6, lane = tid & 63;
    int quad = lane >> 4, m16 = lane & 15;

    // ---- stage neighbor byte-offset table: sIdx[kk][row] = srow*128 ----
    for (int lin = tid; lin < BM * 9; lin += 256) {
        int row = lin / 9, kkq = lin - row * 9;
        int v = -1;
        if (m0 + row < NVOX) v = nbr[(size_t)(m0 + row) * 9 + kkq];
        *(int*)(smem + IDX_OFF + (kkq * BM + row) * 4) = ((v < 0) ? NVOX : v) * 128;
    }
    __syncthreads();

    // preload this lane's 18 gather offsets into registers (static after unroll)
    int off0r[9], off1r[9];
#pragma unroll
    for (int kk = 0; kk < 9; ++kk) {
        off0r[kk] = *(const int*)(smem + IDX_OFF + (kk * BM + lane) * 4);
        off1r[kk] = *(const int*)(smem + IDX_OFF + (kk * BM + 64 + lane) * 4);
    }

    f32x4 acc[4][2];
#pragma unroll
    for (int mt = 0; mt < 4; ++mt)
#pragma unroll
        for (int nt = 0; nt < 2; ++nt)
            acc[mt][nt] = (f32x4){0.f, 0.f, 0.f, 0.f};

    const char* fb = (const char*)featB;
    const char* bsrc = (const char*)Bt2 + (size_t)ntile * 73728;  // head base (bytes)
    char* sAb[2] = {smem, smem + 16384};
    char* sBb[2] = {smem + 32768, smem + 40960};

    int mrow = (w >> 1) * 64;   // wave's row half
    int ncol = (w & 1) * 32;    // wave's col half
    int c16a = w * 2, c16b = w * 2 + 1;

    auto stage = [&](char* sA, char* sB, int kk, int off0, int off1) {
        // A: 4 async 1KB gathers (64 rows x 16B chunk each); LDS dst wave-uniform
        gld16(fb + off0 + c16a * 16, sA + c16a * 2048);
        gld16(fb + off1 + c16a * 16, sA + c16a * 2048 + 1024);
        gld16(fb + off0 + c16b * 16, sA + c16b * 2048);
        gld16(fb + off1 + c16b * 16, sA + c16b * 2048 + 1024);
        // B: 2 async 1KB sequential copies (chunk-major source layout)
        gld16(bsrc + (kk * 8 + c16a) * 1024 + lane * 16, sB + c16a * 1024);
        gld16(bsrc + (kk * 8 + c16b) * 1024 + lane * 16, sB + c16b * 1024);
    };

    // prologue: stage kk=0 into buf0
    stage(sAb[0], sBb[0], 0, off0r[0], off1r[0]);
    __syncthreads();

#pragma unroll
    for (int kk = 0; kk < 9; ++kk) {
        const int cur = kk & 1;
        if (kk < 8)   // issue next tile's loads BEFORE compute: latency hides under MFMA
            stage(sAb[cur ^ 1], sBb[cur ^ 1], kk + 1, off0r[kk + 1], off1r[kk + 1]);
        // ---- compute from buf[cur]: 12 ds_read_b128 + 16 MFMAs ----
        bf16x8 af[2][4], bfr[2][2];
#pragma unroll
        for (int ks = 0; ks < 2; ++ks) {
#pragma unroll
            for (int mt = 0; mt < 4; ++mt)
                af[ks][mt] = *(const bf16x8*)(sAb[cur] + (ks * 4 + quad) * 2048 +
                                              (mrow + mt * 16 + m16) * 16);
#pragma unroll
            for (int nt = 0; nt < 2; ++nt)
                bfr[ks][nt] = *(const bf16x8*)(sBb[cur] + (ks * 4 + quad) * 1024 +
                                               (ncol + nt * 16 + m16) * 16);
        }
#pragma unroll
        for (int ks = 0; ks < 2; ++ks)
#pragma unroll
            for (int mt = 0; mt < 4; ++mt)
#pragma unroll
                for (int nt = 0; nt < 2; ++nt)
                    acc[mt][nt] = __builtin_amdgcn_mfma_f32_16x16x32_bf16(
                        af[ks][mt], bfr[ks][nt], acc[mt][nt], 0, 0, 0);
        __syncthreads();  // one barrier/iter: drains prefetch (vmcnt 0) + protects buf swap
    }

    // ---- epilogue 1: transpose via LDS (aliases dead sA dbuf), coalesced column stores
#pragma unroll
    for (int mt = 0; mt < 4; ++mt) {
#pragma unroll
        for (int nt = 0; nt < 2; ++nt) {
            int col = ncol + nt * 16 + m16;
            int row = mrow + mt * 16 + quad * 4;
            f32x4 v = acc[mt][nt];
            unsigned lo = (unsigned)f2bf(v.x) | ((unsigned)f2bf(v.y) << 16);
            unsigned hi = (unsigned)f2bf(v.z) | ((unsigned)f2bf(v.w) << 16);
            uint2 pk; pk.x = lo; pk.y = hi;
            *(uint2*)(smem + col * 272 + row * 2) = pk;   // col stride 136 ushorts
        }
    }
    __syncthreads();
#pragma unroll
    for (int it = 0; it < 8; ++it) {
        int col = it * 8 + (tid >> 5);
        int l32 = tid & 31;
        uint2 v = *(const uint2*)(smem + col * 272 + l32 * 8);
        *(uint2*)(hbuf + (size_t)(n0 + col) * SROW + m0 + l32 * 4) = v;  // 256B runs
    }

    // ---- epilogue 2: BN statistics (pad/invalid rows are exact zeros) ----
    float s[2], ss[2];
#pragma unroll
    for (int nt = 0; nt < 2; ++nt) {
        float a = 0.f, b = 0.f;
#pragma unroll
        for (int mt = 0; mt < 4; ++mt) {
            f32x4 v = acc[mt][nt];
            a += v.x + v.y + v.z + v.w;
            b += v.x * v.x + v.y * v.y + v.z * v.z + v.w * v.w;
        }
        s[nt] = a; ss[nt] = b;
        s[nt] += __shfl_xor(s[nt], 16); s[nt] += __shfl_xor(s[nt], 32);
        ss[nt] += __shfl_xor(ss[nt], 16); ss[nt] += __shfl_xor(ss[nt], 32);
    }
    if (quad == 0) {
#pragma unroll
        for (int nt = 0; nt < 2; ++nt) {
            float* p = (float*)(smem + SRED_OFF + ((w * 2 + nt) * 16 + m16) * 8);
            p[0] = s[nt]; p[1] = ss[nt];
        }
    }
    __syncthreads();
    if (tid < 64) {
        int col = tid;
        int half = col >> 5, nt = (col >> 4) & 1, mc = col & 15;
        const float* p0 = (const float*)(smem + SRED_OFF + ((half * 2 + nt) * 16 + mc) * 8);
        const float* p1 = (const float*)(smem + SRED_OFF + (((2 + half) * 2 + nt) * 16 + mc) * 8);
        atomicAdd(&stats[n0 + col], p0[0] + p1[0]);
        atomicAdd(&stats[NCOL + n0 + col], p0[1] + p1[1]);
    }
}

// ------- pass 2: BN + ReLU + 1x1 conv, per-HEAD grid (5x parallelism, 64 loads/thread)
__global__ __launch_bounds__(256)
void head_kernel(const unsigned short* __restrict__ hbuf,
                 const float* __restrict__ stats,
                 const float* __restrict__ gamma, const float* __restrict__ beta,
                 const float* __restrict__ W1_0, const float* __restrict__ W1_1,
                 const float* __restrict__ W1_2, const float* __restrict__ W1_3,
                 const float* __restrict__ W1_4,
                 const float* __restrict__ b1_0, const float* __restrict__ b1_1,
                 const float* __restrict__ b1_2, const float* __restrict__ b1_3,
                 const float* __restrict__ b1_4,
                 float* __restrict__ out) {
    __shared__ float sScale[64], sShift[64], sW1[192], sB1[3];
    int h = blockIdx.y;
    const float* W1; const float* b1; int oc; size_t obase;
    if (h == 0)      { W1 = W1_0; b1 = b1_0; oc = 3; obase = 0; }
    else if (h == 1) { W1 = W1_1; b1 = b1_1; oc = 2; obase = 450000; }
    else if (h == 2) { W1 = W1_2; b1 = b1_2; oc = 1; obase = 750000; }
    else if (h == 3) { W1 = W1_3; b1 = b1_3; oc = 3; obase = 900000; }
    else             { W1 = W1_4; b1 = b1_4; oc = 2; obase = 1350000; }

    int tid = threadIdx.x;
    if (tid < 64) {
        int c = h * 64 + tid;
        float mean = stats[c] * (1.f / (float)NVOX);
        float var = stats[NCOL + c] * (1.f / (float)NVOX) - mean * mean;
        float inv = rsqrtf(var + 1e-5f);
        float sc = inv * gamma[c];
        sScale[tid] = sc;
        sShift[tid] = beta[c] - mean * sc;
    }
    for (int i = tid; i < 192; i += 256) {
        int cc = i / 3, jj = i - cc * 3;
        sW1[i] = (jj < oc) ? W1[cc * oc + jj] : 0.f;
    }
    if (tid == 0) {
        sB1[0] = b1[0];
        sB1[1] = (oc >= 2) ? b1[1] : 0.f;
        sB1[2] = (oc >= 3) ? b1[2] : 0.f;
    }
    __syncthreads();

    int n = (blockIdx.x * 256 + tid) * 4;    // 4 rows per thread (NVOX % 4 == 0)
    if (n >= NVOX) return;
    const unsigned short* hp = hbuf + (size_t)(h * 64) * SROW + n;
    float x[4][3];
#pragma unroll
    for (int rr = 0; rr < 4; ++rr) { x[rr][0] = sB1[0]; x[rr][1] = sB1[1]; x[rr][2] = sB1[2]; }
#pragma unroll 8
    for (int cc = 0; cc < 64; ++cc) {
        uint2 raw = *(const uint2*)(hp + (size_t)cc * SROW);   // rows n..n+3, bf16
        float sc = sScale[cc], sh = sShift[cc];
        float w0 = sW1[cc * 3 + 0], w1 = sW1[cc * 3 + 1], w2 = sW1[cc * 3 + 2];
        float v0 = __builtin_bit_cast(float, raw.x << 16);
        float v1 = __builtin_bit_cast(float, raw.x & 0xffff0000u);
        float v2 = __builtin_bit_cast(float, raw.y << 16);
        float v3 = __builtin_bit_cast(float, raw.y & 0xffff0000u);
        v0 = fmaxf(v0 * sc + sh, 0.f); v1 = fmaxf(v1 * sc + sh, 0.f);
        v2 = fmaxf(v2 * sc + sh, 0.f); v3 = fmaxf(v3 * sc + sh, 0.f);
        x[0][0] += v0 * w0; x[0][1] += v0 * w1; x[0][2] += v0 * w2;
        x[1][0] += v1 * w0; x[1][1] += v1 * w1; x[1][2] += v1 * w2;
        x[2][0] += v2 * w0; x[2][1] += v2 * w1; x[2][2] += v2 * w2;
        x[3][0] += v3 * w0; x[3][1] += v3 * w1; x[3][2] += v3 * w2;
    }
#pragma unroll
    for (int rr = 0; rr < 4; ++rr) {
        float* op = out + obase + (size_t)(n + rr) * oc;
        op[0] = x[rr][0];                 // oc is block-uniform; x indices all static
        if (oc >= 2) op[1] = x[rr][1];
        if (oc >= 3) op[2] = x[rr][2];
    }
}

extern "C" void kernel_launch(void* const* d_in, const int* in_sizes, int n_in,
                              void* d_out, int out_size, void* d_ws, size_t ws_size,
                              hipStream_t stream) {
    const float* features = (const float*)d_in[0];
    const int* nbr        = (const int*)d_in[1];
    const float* w3       = (const float*)d_in[2];
    const float* gamma    = (const float*)d_in[3];
    const float* beta     = (const float*)d_in[4];
    const float* W1_0 = (const float*)d_in[5];  const float* b1_0 = (const float*)d_in[6];
    const float* W1_1 = (const float*)d_in[7];  const float* b1_1 = (const float*)d_in[8];
    const float* W1_2 = (const float*)d_in[9];  const float* b1_2 = (const float*)d_in[10];
    const float* W1_3 = (const float*)d_in[11]; const float* b1_3 = (const float*)d_in[12];
    const float* W1_4 = (const float*)d_in[13]; const float* b1_4 = (const float*)d_in[14];
    float* out = (float*)d_out;

    char* ws = (char*)d_ws;
    unsigned short* featB = (unsigned short*)ws;               // (150000+1)*64 bf16
    unsigned short* Bt2   = (unsigned short*)(ws + 19200128);  // 5*9*8*512 bf16
    float* stats          = (float*)(ws + 19568768);           // 640 f32
    unsigned short* hbuf  = (unsigned short*)(ws + 19571328);  // 320*150016 bf16

    prep_feat<<<(NVOX * 8 + 8 + 255) / 256, 256, 0, stream>>>(features, featB);
    prep_w3<<<184320 / 256, 256, 0, stream>>>(w3, Bt2, stats);
    gemm_kernel<<<8 * 5 * 147, 256, 0, stream>>>(featB, Bt2, nbr, hbuf, stats);
    head_kernel<<<dim3(147, 5), 256, 0, stream>>>(hbuf, stats, gamma, beta,
        W1_0, W1_1, W1_2, W1_3, W1_4, b1_0, b1_1, b1_2, b1_3, b1_4, out);
}

// Round 2
// 223.713 us; speedup vs baseline: 1.0207x; 1.0044x over previous
//
#include <hip/hip_runtime.h>

#define NVOX 150000
#define BM 128
#define MTILES 1172         // ceil(150000/128)
#define SROW 150016         // 1172*128, column stride of h buffer
#define NCOL 320

typedef __attribute__((ext_vector_type(8))) short bf16x8;
typedef __attribute__((ext_vector_type(4))) float f32x4;

__device__ __forceinline__ unsigned short f2bf(float f) {
    unsigned u = __builtin_bit_cast(unsigned, f);
    u += 0x7fffu + ((u >> 16) & 1u);
    return (unsigned short)(u >> 16);
}

__device__ __forceinline__ void gld16(const void* g, void* l) {
    __builtin_amdgcn_global_load_lds(
        (const __attribute__((address_space(1))) unsigned int*)g,
        (__attribute__((address_space(3))) unsigned int*)l, 16, 0, 0);
}

// ---------------- prep: features f32 -> bf16 (+ zero row at NVOX), x8 vectorized ------
__global__ void prep_feat(const float* __restrict__ src, unsigned short* __restrict__ dst) {
    int i = blockIdx.x * 256 + threadIdx.x;   // each i handles 8 elements
    if (i < NVOX * 8) {
        const float* s = src + (size_t)i * 8;
        float4 a = *(const float4*)s;
        float4 b = *(const float4*)(s + 4);
        union { bf16x8 v; unsigned short u[8]; } r;
        r.u[0] = f2bf(a.x); r.u[1] = f2bf(a.y); r.u[2] = f2bf(a.z); r.u[3] = f2bf(a.w);
        r.u[4] = f2bf(b.x); r.u[5] = f2bf(b.y); r.u[6] = f2bf(b.z); r.u[7] = f2bf(b.w);
        *(bf16x8*)(dst + (size_t)i * 8) = r.v;
    } else if (i < NVOX * 8 + 8) {            // zero row for invalid/pad gathers
        bf16x8 z = {0, 0, 0, 0, 0, 0, 0, 0};
        *(bf16x8*)(dst + (size_t)i * 8) = z;
    }
}

// ---- prep: W3[h][kk][c][o] f32 -> Bt2 chunk-major bf16: [(h*9+kk)*8 + c16][o][c&7] ----
__global__ void prep_w3(const float* __restrict__ w3, unsigned short* __restrict__ bt,
                        float* __restrict__ stats) {
    int i = blockIdx.x * 256 + threadIdx.x;   // grid is exactly 184320 threads
    int h = i / 36864;
    int rem = i - h * 36864;
    int kk = rem >> 12;
    int c = (rem >> 6) & 63;
    int o = rem & 63;
    bt[(size_t)(((h * 9 + kk) * 8) + (c >> 3)) * 512 + o * 8 + (c & 7)] = f2bf(w3[i]);
    if (i < 2 * NCOL) stats[i] = 0.f;
}

// ---------------- gather-GEMM: TRUE counted-vmcnt double-buffered pipeline -----------
// BM=128, BN=64 (one head), BK=64 (one kk), 4 waves, wave tile 64x32.
// A: gld16 into LDS dbuf (2x16KB). B: global->register, prefetched 1 kk ahead (L2-hot).
// Per iter: stage tile kk+1 (4 gld16 + 4 B loads = 8 vm ops, pinned by "memory" asm
// fences) -> s_waitcnt vmcnt(8) (waits tile kk ONLY; tile kk+1 stays in flight across
// BOTH raw s_barriers) -> barrier -> compute -> barrier. No vmcnt(0) drain in the loop.
// LDS: sA dbuf 2x16KB @0, idx @32768 (4608B) = 37376 -> 4 blocks/CU.
__global__ __launch_bounds__(256, 4)
void gemm_kernel(const unsigned short* __restrict__ featB,
                 const unsigned short* __restrict__ Bt2,
                 const int* __restrict__ nbr,
                 unsigned short* __restrict__ hbuf,
                 float* __restrict__ stats) {
    __shared__ __align__(16) char smem[37376];
    constexpr int IDX_OFF = 32768;   // 9*128 int byte-offsets
    constexpr int SRED_OFF = 32768;  // aliases idx region (dead in epilogue 2)

    // XCD swizzle: the 5 head-blocks of one mtile share bid%8 -> same XCD (A L2 reuse)
    int bid = blockIdx.x;
    int r = bid & 7, q = bid >> 3;
    int ntile = q % 5;
    int mtile = (q / 5) * 8 + r;
    if (mtile >= MTILES) return;
    int m0 = mtile * BM;
    int n0 = ntile * 64;

    int tid = threadIdx.x;
    int w = tid >> 6, lane = tid & 63;
    int quad = lane >> 4, m16 = lane & 15;

    // ---- stage neighbor byte-offset table: sIdx[kk][row] = srow*128 ----
    for (int lin = tid; lin < BM * 9; lin += 256) {
        int row = lin / 9, kkq = lin - row * 9;
        int v = -1;
        if (m0 + row < NVOX) v = nbr[(size_t)(m0 + row) * 9 + kkq];
        *(int*)(smem + IDX_OFF + (kkq * BM + row) * 4) = ((v < 0) ? NVOX : v) * 128;
    }
    __syncthreads();

    f32x4 acc[4][2];
#pragma unroll
    for (int mt = 0; mt < 4; ++mt)
#pragma unroll
        for (int nt = 0; nt < 2; ++nt)
            acc[mt][nt] = (f32x4){0.f, 0.f, 0.f, 0.f};

    const char* fb = (const char*)featB;
    const char* bsrc = (const char*)Bt2 + (size_t)ntile * 73728;  // head base (bytes)
    char* sAb[2] = {smem, smem + 16384};

    int mrow = (w >> 1) * 64;   // wave's row half
    int ncol = (w & 1) * 32;    // wave's col half
    int c16a = w * 2, c16b = w * 2 + 1;
    // per-lane B base: frag(ks,nt,kk) = bb + kk*8192 + ks*4096 + nt*256
    const char* bb = bsrc + quad * 1024 + (ncol + m16) * 16;

    bf16x8 bfr[2][2][2];   // [parity][ks][nt] — parity index is compile-time after unroll

    auto stageA = [&](char* sA, int off0, int off1) {
        // 4 async 1KB gathers (64 rows x 16B chunk each); LDS dst wave-uniform
        gld16(fb + off0 + c16a * 16, sA + c16a * 2048);
        gld16(fb + off1 + c16a * 16, sA + c16a * 2048 + 1024);
        gld16(fb + off0 + c16b * 16, sA + c16b * 2048);
        gld16(fb + off1 + c16b * 16, sA + c16b * 2048 + 1024);
    };

    // prologue: stage tile 0 (4 gld16 + 4 B reg loads = 8 vm ops outstanding)
    {
        int o0 = *(const int*)(smem + IDX_OFF + lane * 4);
        int o1 = *(const int*)(smem + IDX_OFF + (64 + lane) * 4);
        bfr[0][0][0] = *(const bf16x8*)(bb);
        bfr[0][0][1] = *(const bf16x8*)(bb + 256);
        bfr[0][1][0] = *(const bf16x8*)(bb + 4096);
        bfr[0][1][1] = *(const bf16x8*)(bb + 4352);
        stageA(sAb[0], o0, o1);
    }

#pragma unroll
    for (int kk = 0; kk < 9; ++kk) {
        const int p = kk & 1;
        if (kk < 8) {
            // ---- stage tile kk+1: exactly 8 vm ops in this region ----
            int o0 = *(const int*)(smem + IDX_OFF + ((kk + 1) * BM + lane) * 4);
            int o1 = *(const int*)(smem + IDX_OFF + ((kk + 1) * BM + 64 + lane) * 4);
            const char* bk = bb + (size_t)(kk + 1) * 8192;
            bfr[p ^ 1][0][0] = *(const bf16x8*)(bk);
            bfr[p ^ 1][0][1] = *(const bf16x8*)(bk + 256);
            bfr[p ^ 1][1][0] = *(const bf16x8*)(bk + 4096);
            bfr[p ^ 1][1][1] = *(const bf16x8*)(bk + 4352);
            stageA(sAb[p ^ 1], o0, o1);
            // wait tile kk (all ops older than the 8 just issued); kk+1 stays in flight
            asm volatile("s_waitcnt vmcnt(8)" ::: "memory");
        } else {
            asm volatile("s_waitcnt vmcnt(0)" ::: "memory");
        }
        asm volatile("s_barrier" ::: "memory");      // raw barrier: NO vmcnt drain
        __builtin_amdgcn_sched_barrier(0);           // rule 18: pin ds_read/MFMA below
        // ---- compute tile kk: 8 ds_read_b128 + 16 MFMAs ----
        __builtin_amdgcn_s_setprio(1);
#pragma unroll
        for (int ks = 0; ks < 2; ++ks) {
            bf16x8 af[4];
#pragma unroll
            for (int mt = 0; mt < 4; ++mt)
                af[mt] = *(const bf16x8*)(sAb[p] + (ks * 4 + quad) * 2048 +
                                          (mrow + mt * 16 + m16) * 16);
#pragma unroll
            for (int mt = 0; mt < 4; ++mt)
#pragma unroll
                for (int nt = 0; nt < 2; ++nt)
                    acc[mt][nt] = __builtin_amdgcn_mfma_f32_16x16x32_bf16(
                        af[mt], bfr[p][ks][nt], acc[mt][nt], 0, 0, 0);
        }
        __builtin_amdgcn_s_setprio(0);
        __builtin_amdgcn_sched_barrier(0);
        // all waves done reading sAb[p] before next iter restages it (no drain)
        asm volatile("s_barrier" ::: "memory");
    }

    // ---- epilogue 1: transpose via LDS (aliases dead sA dbuf), coalesced column stores
#pragma unroll
    for (int mt = 0; mt < 4; ++mt) {
#pragma unroll
        for (int nt = 0; nt < 2; ++nt) {
            int col = ncol + nt * 16 + m16;
            int row = mrow + mt * 16 + quad * 4;
            f32x4 v = acc[mt][nt];
            unsigned lo = (unsigned)f2bf(v.x) | ((unsigned)f2bf(v.y) << 16);
            unsigned hi = (unsigned)f2bf(v.z) | ((unsigned)f2bf(v.w) << 16);
            uint2 pk; pk.x = lo; pk.y = hi;
            *(uint2*)(smem + col * 272 + row * 2) = pk;   // col stride 136 ushorts
        }
    }
    __syncthreads();
#pragma unroll
    for (int it = 0; it < 8; ++it) {
        int col = it * 8 + (tid >> 5);
        int l32 = tid & 31;
        uint2 v = *(const uint2*)(smem + col * 272 + l32 * 8);
        *(uint2*)(hbuf + (size_t)(n0 + col) * SROW + m0 + l32 * 4) = v;  // 256B runs
    }

    // ---- epilogue 2: BN statistics (pad/invalid rows are exact zeros) ----
    float s[2], ss[2];
#pragma unroll
    for (int nt = 0; nt < 2; ++nt) {
        float a = 0.f, b = 0.f;
#pragma unroll
        for (int mt = 0; mt < 4; ++mt) {
            f32x4 v = acc[mt][nt];
            a += v.x + v.y + v.z + v.w;
            b += v.x * v.x + v.y * v.y + v.z * v.z + v.w * v.w;
        }
        s[nt] = a; ss[nt] = b;
        s[nt] += __shfl_xor(s[nt], 16); s[nt] += __shfl_xor(s[nt], 32);
        ss[nt] += __shfl_xor(ss[nt], 16); ss[nt] += __shfl_xor(ss[nt], 32);
    }
    if (quad == 0) {
#pragma unroll
        for (int nt = 0; nt < 2; ++nt) {
            float* p = (float*)(smem + SRED_OFF + ((w * 2 + nt) * 16 + m16) * 8);
            p[0] = s[nt]; p[1] = ss[nt];
        }
    }
    __syncthreads();
    if (tid < 64) {
        int col = tid;
        int half = col >> 5, nt = (col >> 4) & 1, mc = col & 15;
        const float* p0 = (const float*)(smem + SRED_OFF + ((half * 2 + nt) * 16 + mc) * 8);
        const float* p1 = (const float*)(smem + SRED_OFF + (((2 + half) * 2 + nt) * 16 + mc) * 8);
        atomicAdd(&stats[n0 + col], p0[0] + p1[0]);
        atomicAdd(&stats[NCOL + n0 + col], p0[1] + p1[1]);
    }
}

// ------- pass 2: BN + ReLU + 1x1 conv, per-HEAD grid (5x parallelism, 64 loads/thread)
__global__ __launch_bounds__(256)
void head_kernel(const unsigned short* __restrict__ hbuf,
                 const float* __restrict__ stats,
                 const float* __restrict__ gamma, const float* __restrict__ beta,
                 const float* __restrict__ W1_0, const float* __restrict__ W1_1,
                 const float* __restrict__ W1_2, const float* __restrict__ W1_3,
                 const float* __restrict__ W1_4,
                 const float* __restrict__ b1_0, const float* __restrict__ b1_1,
                 const float* __restrict__ b1_2, const float* __restrict__ b1_3,
                 const float* __restrict__ b1_4,
                 float* __restrict__ out) {
    __shared__ float sScale[64], sShift[64], sW1[192], sB1[3];
    int h = blockIdx.y;
    const float* W1; const float* b1; int oc; size_t obase;
    if (h == 0)      { W1 = W1_0; b1 = b1_0; oc = 3; obase = 0; }
    else if (h == 1) { W1 = W1_1; b1 = b1_1; oc = 2; obase = 450000; }
    else if (h == 2) { W1 = W1_2; b1 = b1_2; oc = 1; obase = 750000; }
    else if (h == 3) { W1 = W1_3; b1 = b1_3; oc = 3; obase = 900000; }
    else             { W1 = W1_4; b1 = b1_4; oc = 2; obase = 1350000; }

    int tid = threadIdx.x;
    if (tid < 64) {
        int c = h * 64 + tid;
        float mean = stats[c] * (1.f / (float)NVOX);
        float var = stats[NCOL + c] * (1.f / (float)NVOX) - mean * mean;
        float inv = rsqrtf(var + 1e-5f);
        float sc = inv * gamma[c];
        sScale[tid] = sc;
        sShift[tid] = beta[c] - mean * sc;
    }
    for (int i = tid; i < 192; i += 256) {
        int cc = i / 3, jj = i - cc * 3;
        sW1[i] = (jj < oc) ? W1[cc * oc + jj] : 0.f;
    }
    if (tid == 0) {
        sB1[0] = b1[0];
        sB1[1] = (oc >= 2) ? b1[1] : 0.f;
        sB1[2] = (oc >= 3) ? b1[2] : 0.f;
    }
    __syncthreads();

    int n = (blockIdx.x * 256 + tid) * 4;    // 4 rows per thread (NVOX % 4 == 0)
    if (n >= NVOX) return;
    const unsigned short* hp = hbuf + (size_t)(h * 64) * SROW + n;
    float x[4][3];
#pragma unroll
    for (int rr = 0; rr < 4; ++rr) { x[rr][0] = sB1[0]; x[rr][1] = sB1[1]; x[rr][2] = sB1[2]; }
#pragma unroll 8
    for (int cc = 0; cc < 64; ++cc) {
        uint2 raw = *(const uint2*)(hp + (size_t)cc * SROW);   // rows n..n+3, bf16
        float sc = sScale[cc], sh = sShift[cc];
        float w0 = sW1[cc * 3 + 0], w1 = sW1[cc * 3 + 1], w2 = sW1[cc * 3 + 2];
        float v0 = __builtin_bit_cast(float, raw.x << 16);
        float v1 = __builtin_bit_cast(float, raw.x & 0xffff0000u);
        float v2 = __builtin_bit_cast(float, raw.y << 16);
        float v3 = __builtin_bit_cast(float, raw.y & 0xffff0000u);
        v0 = fmaxf(v0 * sc + sh, 0.f); v1 = fmaxf(v1 * sc + sh, 0.f);
        v2 = fmaxf(v2 * sc + sh, 0.f); v3 = fmaxf(v3 * sc + sh, 0.f);
        x[0][0] += v0 * w0; x[0][1] += v0 * w1; x[0][2] += v0 * w2;
        x[1][0] += v1 * w0; x[1][1] += v1 * w1; x[1][2] += v1 * w2;
        x[2][0] += v2 * w0; x[2][1] += v2 * w1; x[2][2] += v2 * w2;
        x[3][0] += v3 * w0; x[3][1] += v3 * w1; x[3][2] += v3 * w2;
    }
#pragma unroll
    for (int rr = 0; rr < 4; ++rr) {
        float* op = out + obase + (size_t)(n + rr) * oc;
        op[0] = x[rr][0];                 // oc is block-uniform; x indices all static
        if (oc >= 2) op[1] = x[rr][1];
        if (oc >= 3) op[2] = x[rr][2];
    }
}

extern "C" void kernel_launch(void* const* d_in, const int* in_sizes, int n_in,
                              void* d_out, int out_size, void* d_ws, size_t ws_size,
                              hipStream_t stream) {
    const float* features = (const float*)d_in[0];
    const int* nbr        = (const int*)d_in[1];
    const float* w3       = (const float*)d_in[2];
    const float* gamma    = (const float*)d_in[3];
    const float* beta     = (const float*)d_in[4];
    const float* W1_0 = (const float*)d_in[5];  const float* b1_0 = (const float*)d_in[6];
    const float* W1_1 = (const float*)d_in[7];  const float* b1_1 = (const float*)d_in[8];
    const float* W1_2 = (const float*)d_in[9];  const float* b1_2 = (const float*)d_in[10];
    const float* W1_3 = (const float*)d_in[11]; const float* b1_3 = (const float*)d_in[12];
    const float* W1_4 = (const float*)d_in[13]; const float* b1_4 = (const float*)d_in[14];
    float* out = (float*)d_out;

    char* ws = (char*)d_ws;
    unsigned short* featB = (unsigned short*)ws;               // (150000+1)*64 bf16
    unsigned short* Bt2   = (unsigned short*)(ws + 19200128);  // 5*9*8*512 bf16
    float* stats          = (float*)(ws + 19568768);           // 640 f32
    unsigned short* hbuf  = (unsigned short*)(ws + 19571328);  // 320*150016 bf16

    prep_feat<<<(NVOX * 8 + 8 + 255) / 256, 256, 0, stream>>>(features, featB);
    prep_w3<<<184320 / 256, 256, 0, stream>>>(w3, Bt2, stats);
    gemm_kernel<<<8 * 5 * 147, 256, 0, stream>>>(featB, Bt2, nbr, hbuf, stats);
    head_kernel<<<dim3(147, 5), 256, 0, stream>>>(hbuf, stats, gamma, beta,
        W1_0, W1_1, W1_2, W1_3, W1_4, b1_0, b1_1, b1_2, b1_3, b1_4, out);
}

// Round 3
// 219.253 us; speedup vs baseline: 1.0415x; 1.0203x over previous
//
#include <hip/hip_runtime.h>

#define NVOX 150000
#define BM 128
#define MTILES 1172         // ceil(150000/128)
#define SROW 150016         // 1172*128, column stride of h buffer
#define NCOL 320

typedef __attribute__((ext_vector_type(8))) short bf16x8;
typedef __attribute__((ext_vector_type(4))) float f32x4;

__device__ __forceinline__ unsigned short f2bf(float f) {
    unsigned u = __builtin_bit_cast(unsigned, f);
    u += 0x7fffu + ((u >> 16) & 1u);
    return (unsigned short)(u >> 16);
}

__device__ __forceinline__ void gld16(const void* g, void* l) {
    __builtin_amdgcn_global_load_lds(
        (const __attribute__((address_space(1))) unsigned int*)g,
        (__attribute__((address_space(3))) unsigned int*)l, 16, 0, 0);
}

// ---------------- prep: features f32 -> bf16 (+ zero row at NVOX), x8 vectorized ------
__global__ void prep_feat(const float* __restrict__ src, unsigned short* __restrict__ dst) {
    int i = blockIdx.x * 256 + threadIdx.x;   // each i handles 8 elements
    if (i < NVOX * 8) {
        const float* s = src + (size_t)i * 8;
        float4 a = *(const float4*)s;
        float4 b = *(const float4*)(s + 4);
        union { bf16x8 v; unsigned short u[8]; } r;
        r.u[0] = f2bf(a.x); r.u[1] = f2bf(a.y); r.u[2] = f2bf(a.z); r.u[3] = f2bf(a.w);
        r.u[4] = f2bf(b.x); r.u[5] = f2bf(b.y); r.u[6] = f2bf(b.z); r.u[7] = f2bf(b.w);
        *(bf16x8*)(dst + (size_t)i * 8) = r.v;
    } else if (i < NVOX * 8 + 8) {            // zero row for invalid/pad gathers
        bf16x8 z = {0, 0, 0, 0, 0, 0, 0, 0};
        *(bf16x8*)(dst + (size_t)i * 8) = z;
    }
}

// ---- prep: W3[h][kk][c][o] f32 -> Bt2 chunk-major bf16: [(h*9+kk)*8 + c16][o][c&7] ----
__global__ void prep_w3(const float* __restrict__ w3, unsigned short* __restrict__ bt,
                        float* __restrict__ stats) {
    int i = blockIdx.x * 256 + threadIdx.x;   // grid is exactly 184320 threads
    int h = i / 36864;
    int rem = i - h * 36864;
    int kk = rem >> 12;
    int c = (rem >> 6) & 63;
    int o = rem & 63;
    bt[(size_t)(((h * 9 + kk) * 8) + (c >> 3)) * 512 + o * 8 + (c & 7)] = f2bf(w3[i]);
    if (i < 2 * NCOL) stats[i] = 0.f;
}

// ---------------- gather-GEMM: ALL 5 HEADS per block (A gathered ONCE, 5x less) -------
// BM=128, N=320 (all heads), BK=64 (one kk), 8 waves (512 thr), wave tile 64x80.
// A: gld16 LDS dbuf 2x16KB; B: gld16 LDS dbuf 2x40KB (L2-resident, 360KB footprint).
// Counted-vmcnt pipeline: per iter stage kk+1 (2 A + 5 B = 7 vm ops/wave) ->
// s_waitcnt vmcnt(7) (tile kk ready, kk+1 in flight across both raw s_barriers).
// LDS: sA 2x16K @0, sB 2x40K @32768, idx @114688 -> 119296 B, 1 block/CU (8 waves).
__global__ __launch_bounds__(512, 2)
void gemm_kernel(const unsigned short* __restrict__ featB,
                 const unsigned short* __restrict__ Bt2,
                 const int* __restrict__ nbr,
                 unsigned short* __restrict__ hbuf,
                 float* __restrict__ stats) {
    __shared__ __align__(16) char smem[119296];
    constexpr int SB_OFF = 32768;    // B dbuf 2x40960
    constexpr int IDX_OFF = 114688;  // 9*128 int byte-offsets (4608 B)
    constexpr int SRED_OFF = 88064;  // stats staging 8*80*8 B; above transpose's 87040

    int mtile = blockIdx.x;
    int m0 = mtile * BM;

    int tid = threadIdx.x;
    int w = tid >> 6, lane = tid & 63;
    int quad = lane >> 4, m16 = lane & 15;

    // ---- stage neighbor byte-offset table: sIdx[kk][row] = srow*128 ----
    for (int lin = tid; lin < BM * 9; lin += 512) {
        int row = lin / 9, kkq = lin - row * 9;
        int v = -1;
        if (m0 + row < NVOX) v = nbr[(size_t)(m0 + row) * 9 + kkq];
        *(int*)(smem + IDX_OFF + (kkq * BM + row) * 4) = ((v < 0) ? NVOX : v) * 128;
    }
    __syncthreads();

    f32x4 acc[4][5];
#pragma unroll
    for (int mt = 0; mt < 4; ++mt)
#pragma unroll
        for (int nt = 0; nt < 5; ++nt)
            acc[mt][nt] = (f32x4){0.f, 0.f, 0.f, 0.f};

    const char* fb = (const char*)featB;
    const char* bt = (const char*)Bt2;
    char* sAb[2] = {smem, smem + 16384};
    char* sBb[2] = {smem + SB_OFF, smem + SB_OFF + 40960};

    int mrow = (w >> 2) * 64;    // wave's row half (0/64)
    int half = w >> 2;
    int cbase = (w & 3) * 80;    // wave's 80-col quarter of the 320 cols

    // B stage units for this wave: u = w*5+j -> (head, c16); 8 waves x 5 = 40 KB/kk
    int bsj[5], bdj[5];
#pragma unroll
    for (int j = 0; j < 5; ++j) {
        int u = w * 5 + j;
        int h = u >> 3, c16 = u & 7;
        bsj[j] = (h * 72 + c16) * 1024 + lane * 16;  // + kk*8192 per tile
        bdj[j] = (h * 8 + c16) * 1024;
    }
    // per-lane B-frag byte offsets within sB: col -> (head, o) chunk-major
    int sBoff[5];
#pragma unroll
    for (int nt = 0; nt < 5; ++nt) {
        int c = cbase + nt * 16 + m16;
        sBoff[nt] = (c >> 6) * 8192 + (c & 63) * 16;
    }

    auto stage = [&](int buf, int kk) {
        int off0 = *(const int*)(smem + IDX_OFF + (kk * BM + lane) * 4);
        int off1 = *(const int*)(smem + IDX_OFF + (kk * BM + 64 + lane) * 4);
        char* sA = sAb[buf];
        char* sB = sBb[buf];
        // A: wave w owns 16B-chunk w of all 128 rows (2 x 1KB gathers)
        gld16(fb + off0 + w * 16, sA + w * 2048);
        gld16(fb + off1 + w * 16, sA + w * 2048 + 1024);
        // B: 5 sequential 1KB copies (chunk-major source), L2-hot
#pragma unroll
        for (int j = 0; j < 5; ++j)
            gld16(bt + (size_t)(bsj[j] + kk * 8192), sB + bdj[j]);
    };

    // prologue: stage tile 0 (7 vm ops in flight)
    stage(0, 0);

#pragma unroll
    for (int kk = 0; kk < 9; ++kk) {
        const int p = kk & 1;
        if (kk < 8) {
            stage(p ^ 1, kk + 1);                      // 7 more vm ops (14 in flight)
            asm volatile("s_waitcnt vmcnt(7)" ::: "memory");  // tile kk done; kk+1 flies
        } else {
            asm volatile("s_waitcnt vmcnt(0)" ::: "memory");
        }
        asm volatile("s_barrier" ::: "memory");        // raw barrier: NO vmcnt drain
        __builtin_amdgcn_sched_barrier(0);             // rule 18: pin ds_read/MFMA below
        __builtin_amdgcn_s_setprio(1);
#pragma unroll
        for (int ks = 0; ks < 2; ++ks) {
            bf16x8 af[4], bf[5];
#pragma unroll
            for (int mt = 0; mt < 4; ++mt)
                af[mt] = *(const bf16x8*)(sAb[p] + (ks * 4 + quad) * 2048 +
                                          half * 1024 + (mt * 16 + m16) * 16);
#pragma unroll
            for (int nt = 0; nt < 5; ++nt)
                bf[nt] = *(const bf16x8*)(sBb[p] + sBoff[nt] + (ks * 4 + quad) * 1024);
#pragma unroll
            for (int mt = 0; mt < 4; ++mt)
#pragma unroll
                for (int nt = 0; nt < 5; ++nt)
                    acc[mt][nt] = __builtin_amdgcn_mfma_f32_16x16x32_bf16(
                        af[mt], bf[nt], acc[mt][nt], 0, 0, 0);
        }
        __builtin_amdgcn_s_setprio(0);
        __builtin_amdgcn_sched_barrier(0);
        asm volatile("s_barrier" ::: "memory");        // sAb[p]/sBb[p] free to restage
    }

    // ---- epilogue 1: transpose via LDS (aliases dead sA/sB), coalesced column stores
#pragma unroll
    for (int mt = 0; mt < 4; ++mt) {
#pragma unroll
        for (int nt = 0; nt < 5; ++nt) {
            int col = cbase + nt * 16 + m16;
            int row = mrow + mt * 16 + quad * 4;
            f32x4 v = acc[mt][nt];
            unsigned lo = (unsigned)f2bf(v.x) | ((unsigned)f2bf(v.y) << 16);
            unsigned hi = (unsigned)f2bf(v.z) | ((unsigned)f2bf(v.w) << 16);
            uint2 pk; pk.x = lo; pk.y = hi;
            *(uint2*)(smem + col * 272 + row * 2) = pk;   // col stride 136 ushorts
        }
    }
    __syncthreads();
#pragma unroll
    for (int it = 0; it < 20; ++it) {                  // 320 cols = 20 x (16 cols x 32 ln)
        int col = it * 16 + (tid >> 5);
        int l32 = tid & 31;
        uint2 v = *(const uint2*)(smem + col * 272 + l32 * 8);
        *(uint2*)(hbuf + (size_t)col * SROW + m0 + l32 * 4) = v;  // 256B runs
    }

    // ---- epilogue 2: BN statistics (pad/invalid rows are exact zeros) ----
    float s[5], ss[5];
#pragma unroll
    for (int nt = 0; nt < 5; ++nt) {
        float a = 0.f, b = 0.f;
#pragma unroll
        for (int mt = 0; mt < 4; ++mt) {
            f32x4 v = acc[mt][nt];
            a += v.x + v.y + v.z + v.w;
            b += v.x * v.x + v.y * v.y + v.z * v.z + v.w * v.w;
        }
        s[nt] = a; ss[nt] = b;
        s[nt] += __shfl_xor(s[nt], 16); s[nt] += __shfl_xor(s[nt], 32);
        ss[nt] += __shfl_xor(ss[nt], 16); ss[nt] += __shfl_xor(ss[nt], 32);
    }
    if (quad == 0) {   // SRED region (88064+) does not alias transpose data (<87040)
#pragma unroll
        for (int nt = 0; nt < 5; ++nt) {
            float* p = (float*)(smem + SRED_OFF + (w * 80 + nt * 16 + m16) * 8);
            p[0] = s[nt]; p[1] = ss[nt];
        }
    }
    __syncthreads();
    if (tid < NCOL) {
        int c = tid;
        int qq = c / 80, lc = c - qq * 80;   // waves qq (rows 0-63) and qq+4 (64-127)
        const float* p0 = (const float*)(smem + SRED_OFF + (qq * 80 + lc) * 8);
        const float* p1 = (const float*)(smem + SRED_OFF + ((qq + 4) * 80 + lc) * 8);
        atomicAdd(&stats[c], p0[0] + p1[0]);
        atomicAdd(&stats[NCOL + c], p0[1] + p1[1]);
    }
}

// ------- pass 2: BN + ReLU + 1x1 conv, per-HEAD grid (5x parallelism, 64 loads/thread)
__global__ __launch_bounds__(256)
void head_kernel(const unsigned short* __restrict__ hbuf,
                 const float* __restrict__ stats,
                 const float* __restrict__ gamma, const float* __restrict__ beta,
                 const float* __restrict__ W1_0, const float* __restrict__ W1_1,
                 const float* __restrict__ W1_2, const float* __restrict__ W1_3,
                 const float* __restrict__ W1_4,
                 const float* __restrict__ b1_0, const float* __restrict__ b1_1,
                 const float* __restrict__ b1_2, const float* __restrict__ b1_3,
                 const float* __restrict__ b1_4,
                 float* __restrict__ out) {
    __shared__ float sScale[64], sShift[64], sW1[192], sB1[3];
    int h = blockIdx.y;
    const float* W1; const float* b1; int oc; size_t obase;
    if (h == 0)      { W1 = W1_0; b1 = b1_0; oc = 3; obase = 0; }
    else if (h == 1) { W1 = W1_1; b1 = b1_1; oc = 2; obase = 450000; }
    else if (h == 2) { W1 = W1_2; b1 = b1_2; oc = 1; obase = 750000; }
    else if (h == 3) { W1 = W1_3; b1 = b1_3; oc = 3; obase = 900000; }
    else             { W1 = W1_4; b1 = b1_4; oc = 2; obase = 1350000; }

    int tid = threadIdx.x;
    if (tid < 64) {
        int c = h * 64 + tid;
        float mean = stats[c] * (1.f / (float)NVOX);
        float var = stats[NCOL + c] * (1.f / (float)NVOX) - mean * mean;
        float inv = rsqrtf(var + 1e-5f);
        float sc = inv * gamma[c];
        sScale[tid] = sc;
        sShift[tid] = beta[c] - mean * sc;
    }
    for (int i = tid; i < 192; i += 256) {
        int cc = i / 3, jj = i - cc * 3;
        sW1[i] = (jj < oc) ? W1[cc * oc + jj] : 0.f;
    }
    if (tid == 0) {
        sB1[0] = b1[0];
        sB1[1] = (oc >= 2) ? b1[1] : 0.f;
        sB1[2] = (oc >= 3) ? b1[2] : 0.f;
    }
    __syncthreads();

    int n = (blockIdx.x * 256 + tid) * 4;    // 4 rows per thread (NVOX % 4 == 0)
    if (n >= NVOX) return;
    const unsigned short* hp = hbuf + (size_t)(h * 64) * SROW + n;
    float x[4][3];
#pragma unroll
    for (int rr = 0; rr < 4; ++rr) { x[rr][0] = sB1[0]; x[rr][1] = sB1[1]; x[rr][2] = sB1[2]; }
#pragma unroll 8
    for (int cc = 0; cc < 64; ++cc) {
        uint2 raw = *(const uint2*)(hp + (size_t)cc * SROW);   // rows n..n+3, bf16
        float sc = sScale[cc], sh = sShift[cc];
        float w0 = sW1[cc * 3 + 0], w1 = sW1[cc * 3 + 1], w2 = sW1[cc * 3 + 2];
        float v0 = __builtin_bit_cast(float, raw.x << 16);
        float v1 = __builtin_bit_cast(float, raw.x & 0xffff0000u);
        float v2 = __builtin_bit_cast(float, raw.y << 16);
        float v3 = __builtin_bit_cast(float, raw.y & 0xffff0000u);
        v0 = fmaxf(v0 * sc + sh, 0.f); v1 = fmaxf(v1 * sc + sh, 0.f);
        v2 = fmaxf(v2 * sc + sh, 0.f); v3 = fmaxf(v3 * sc + sh, 0.f);
        x[0][0] += v0 * w0; x[0][1] += v0 * w1; x[0][2] += v0 * w2;
        x[1][0] += v1 * w0; x[1][1] += v1 * w1; x[1][2] += v1 * w2;
        x[2][0] += v2 * w0; x[2][1] += v2 * w1; x[2][2] += v2 * w2;
        x[3][0] += v3 * w0; x[3][1] += v3 * w1; x[3][2] += v3 * w2;
    }
#pragma unroll
    for (int rr = 0; rr < 4; ++rr) {
        float* op = out + obase + (size_t)(n + rr) * oc;
        op[0] = x[rr][0];                 // oc is block-uniform; x indices all static
        if (oc >= 2) op[1] = x[rr][1];
        if (oc >= 3) op[2] = x[rr][2];
    }
}

extern "C" void kernel_launch(void* const* d_in, const int* in_sizes, int n_in,
                              void* d_out, int out_size, void* d_ws, size_t ws_size,
                              hipStream_t stream) {
    const float* features = (const float*)d_in[0];
    const int* nbr        = (const int*)d_in[1];
    const float* w3       = (const float*)d_in[2];
    const float* gamma    = (const float*)d_in[3];
    const float* beta     = (const float*)d_in[4];
    const float* W1_0 = (const float*)d_in[5];  const float* b1_0 = (const float*)d_in[6];
    const float* W1_1 = (const float*)d_in[7];  const float* b1_1 = (const float*)d_in[8];
    const float* W1_2 = (const float*)d_in[9];  const float* b1_2 = (const float*)d_in[10];
    const float* W1_3 = (const float*)d_in[11]; const float* b1_3 = (const float*)d_in[12];
    const float* W1_4 = (const float*)d_in[13]; const float* b1_4 = (const float*)d_in[14];
    float* out = (float*)d_out;

    char* ws = (char*)d_ws;
    unsigned short* featB = (unsigned short*)ws;               // (150000+1)*64 bf16
    unsigned short* Bt2   = (unsigned short*)(ws + 19200128);  // 5*9*8*512 bf16
    float* stats          = (float*)(ws + 19568768);           // 640 f32
    unsigned short* hbuf  = (unsigned short*)(ws + 19571328);  // 320*150016 bf16

    prep_feat<<<(NVOX * 8 + 8 + 255) / 256, 256, 0, stream>>>(features, featB);
    prep_w3<<<184320 / 256, 256, 0, stream>>>(w3, Bt2, stats);
    gemm_kernel<<<MTILES, 512, 0, stream>>>(featB, Bt2, nbr, hbuf, stats);
    head_kernel<<<dim3(147, 5), 256, 0, stream>>>(hbuf, stats, gamma, beta,
        W1_0, W1_1, W1_2, W1_3, W1_4, b1_0, b1_1, b1_2, b1_3, b1_4, out);
}

// Round 4
// 215.318 us; speedup vs baseline: 1.0605x; 1.0183x over previous
//
#include <hip/hip_runtime.h>

#define NVOX 150000
#define BM 128
#define MTILES 1172         // ceil(150000/128)
#define SROW 150016         // 1172*128, column stride of h buffer
#define NCOL 320

typedef __attribute__((ext_vector_type(8))) short bf16x8;
typedef __attribute__((ext_vector_type(4))) float f32x4;

__device__ __forceinline__ unsigned short f2bf(float f) {
    unsigned u = __builtin_bit_cast(unsigned, f);
    u += 0x7fffu + ((u >> 16) & 1u);
    return (unsigned short)(u >> 16);
}

__device__ __forceinline__ void gld16(const void* g, void* l) {
    __builtin_amdgcn_global_load_lds(
        (const __attribute__((address_space(1))) unsigned int*)g,
        (__attribute__((address_space(3))) unsigned int*)l, 16, 0, 0);
}

// ---------------- prep: features f32 -> bf16 (+ zero row at NVOX), x8 vectorized ------
__global__ void prep_feat(const float* __restrict__ src, unsigned short* __restrict__ dst) {
    int i = blockIdx.x * 256 + threadIdx.x;   // each i handles 8 elements
    if (i < NVOX * 8) {
        const float* s = src + (size_t)i * 8;
        float4 a = *(const float4*)s;
        float4 b = *(const float4*)(s + 4);
        union { bf16x8 v; unsigned short u[8]; } r;
        r.u[0] = f2bf(a.x); r.u[1] = f2bf(a.y); r.u[2] = f2bf(a.z); r.u[3] = f2bf(a.w);
        r.u[4] = f2bf(b.x); r.u[5] = f2bf(b.y); r.u[6] = f2bf(b.z); r.u[7] = f2bf(b.w);
        *(bf16x8*)(dst + (size_t)i * 8) = r.v;
    } else if (i < NVOX * 8 + 8) {            // zero row for invalid/pad gathers
        bf16x8 z = {0, 0, 0, 0, 0, 0, 0, 0};
        *(bf16x8*)(dst + (size_t)i * 8) = z;
    }
}

// ---- prep: W3[h][kk][c][o] f32 -> Bt2 chunk-major bf16: [(h*9+kk)*8 + c16][o][c&7] ----
__global__ void prep_w3(const float* __restrict__ w3, unsigned short* __restrict__ bt,
                        float* __restrict__ stats) {
    int i = blockIdx.x * 256 + threadIdx.x;   // grid is exactly 184320 threads
    int h = i / 36864;
    int rem = i - h * 36864;
    int kk = rem >> 12;
    int c = (rem >> 6) & 63;
    int o = rem & 63;
    bt[(size_t)(((h * 9 + kk) * 8) + (c >> 3)) * 512 + o * 8 + (c & 7)] = f2bf(w3[i]);
    if (i < 2 * NCOL) stats[i] = 0.f;
}

// ---------------- gather-GEMM: all 5 heads/block + ROW-COALESCED gather ---------------
// A gather: 8 lanes per row (lane = r*8+j) -> one gld16 = 8 FULL 128B rows = 16 fully-
// used 64B lines (was: 64 random 16B chunks = 64 quarter-used lines). 4x less L3 line
// traffic. LDS dst is row-major [row][128B]; to dodge the 32-way bank conflict on frag
// reads, the SOURCE chunk is XOR-permuted (j ^ (r&7)) and ds_read applies the same XOR
// (T2 swizzle via pre-swizzled global source, m173 pattern). Bytes in regs bit-identical.
// Counted-vmcnt pipeline: stage kk+1 (2 A + 5 B = 7 vm ops/wave) -> s_waitcnt vmcnt(7).
// LDS: sA 2x16K @0, sB 2x40K @32768, idx @114688 -> 119296 B, 1 block/CU (8 waves).
__global__ __launch_bounds__(512, 2)
void gemm_kernel(const unsigned short* __restrict__ featB,
                 const unsigned short* __restrict__ Bt2,
                 const int* __restrict__ nbr,
                 unsigned short* __restrict__ hbuf,
                 float* __restrict__ stats) {
    __shared__ __align__(16) char smem[119296];
    constexpr int SB_OFF = 32768;    // B dbuf 2x40960
    constexpr int IDX_OFF = 114688;  // 9*128 int byte-offsets (4608 B)
    constexpr int SRED_OFF = 88064;  // stats staging 8*80*8 B; above transpose's 87040

    int mtile = blockIdx.x;
    int m0 = mtile * BM;

    int tid = threadIdx.x;
    int w = tid >> 6, lane = tid & 63;
    int quad = lane >> 4, m16 = lane & 15;

    // ---- stage neighbor byte-offset table: sIdx[kk][row] = srow*128 ----
    for (int lin = tid; lin < BM * 9; lin += 512) {
        int row = lin / 9, kkq = lin - row * 9;
        int v = -1;
        if (m0 + row < NVOX) v = nbr[(size_t)(m0 + row) * 9 + kkq];
        *(int*)(smem + IDX_OFF + (kkq * BM + row) * 4) = ((v < 0) ? NVOX : v) * 128;
    }
    __syncthreads();

    f32x4 acc[4][5];
#pragma unroll
    for (int mt = 0; mt < 4; ++mt)
#pragma unroll
        for (int nt = 0; nt < 5; ++nt)
            acc[mt][nt] = (f32x4){0.f, 0.f, 0.f, 0.f};

    const char* fb = (const char*)featB;
    const char* bt = (const char*)Bt2;
    char* sAb[2] = {smem, smem + 16384};
    char* sBb[2] = {smem + SB_OFF, smem + SB_OFF + 40960};

    int mrow = (w >> 2) * 64;    // wave's row half (0/64)
    int cbase = (w & 3) * 80;    // wave's 80-col quarter of the 320 cols

    // gather geometry: 8 lanes per row; lane = rloc*8 + j
    int rloc = lane >> 3, j = lane & 7;
    int jx = (j ^ rloc) * 16;    // source-chunk XOR swizzle ((row&7) == rloc for both instrs)

    // B stage units for this wave: u = w*5+j -> (head, c16); 8 waves x 5 = 40 KB/kk
    int bsj[5], bdj[5];
#pragma unroll
    for (int jj = 0; jj < 5; ++jj) {
        int u = w * 5 + jj;
        int h = u >> 3, c16 = u & 7;
        bsj[jj] = (h * 72 + c16) * 1024 + lane * 16;  // + kk*8192 per tile
        bdj[jj] = (h * 8 + c16) * 1024;
    }
    // per-lane B-frag byte offsets within sB: col -> (head, o) chunk-major
    int sBoff[5];
#pragma unroll
    for (int nt = 0; nt < 5; ++nt) {
        int c = cbase + nt * 16 + m16;
        sBoff[nt] = (c >> 6) * 8192 + (c & 63) * 16;
    }
    // per-lane A-frag row bases (row-major) + XOR term per ds_read
    int aRow[4];
#pragma unroll
    for (int mt = 0; mt < 4; ++mt)
        aRow[mt] = (mrow + mt * 16 + m16) * 128;
    int axor = m16 & 7;          // == row & 7 for all frag rows

    auto stage = [&](int buf, int kk) {
        char* sA = sAb[buf];
        char* sB = sBb[buf];
        // A: wave w stages rows w*16 .. w*16+15 (2 instr x 8 rows); per-lane src
        // addr = rowbase + swizzled chunk; LDS dst wave-uniform (HW adds lane*16)
        int off0 = *(const int*)(smem + IDX_OFF + (kk * BM + w * 16 + rloc) * 4);
        int off1 = *(const int*)(smem + IDX_OFF + (kk * BM + w * 16 + 8 + rloc) * 4);
        gld16(fb + off0 + jx, sA + w * 2048);
        gld16(fb + off1 + jx, sA + w * 2048 + 1024);
        // B: 5 sequential 1KB copies (chunk-major source), L2-hot
#pragma unroll
        for (int jj = 0; jj < 5; ++jj)
            gld16(bt + (size_t)(bsj[jj] + kk * 8192), sB + bdj[jj]);
    };

    // prologue: stage tile 0 (7 vm ops in flight)
    stage(0, 0);

#pragma unroll
    for (int kk = 0; kk < 9; ++kk) {
        const int p = kk & 1;
        if (kk < 8) {
            stage(p ^ 1, kk + 1);                      // 7 more vm ops (14 in flight)
            asm volatile("s_waitcnt vmcnt(7)" ::: "memory");  // tile kk done; kk+1 flies
        } else {
            asm volatile("s_waitcnt vmcnt(0)" ::: "memory");
        }
        asm volatile("s_barrier" ::: "memory");        // raw barrier: NO vmcnt drain
        __builtin_amdgcn_sched_barrier(0);             // rule 18: pin ds_read/MFMA below
        __builtin_amdgcn_s_setprio(1);
#pragma unroll
        for (int ks = 0; ks < 2; ++ks) {
            bf16x8 af[4], bf[5];
            int xq = ((ks * 4 + quad) ^ axor) * 16;    // swizzled chunk within row
#pragma unroll
            for (int mt = 0; mt < 4; ++mt)
                af[mt] = *(const bf16x8*)(sAb[p] + aRow[mt] + xq);
#pragma unroll
            for (int nt = 0; nt < 5; ++nt)
                bf[nt] = *(const bf16x8*)(sBb[p] + sBoff[nt] + (ks * 4 + quad) * 1024);
#pragma unroll
            for (int mt = 0; mt < 4; ++mt)
#pragma unroll
                for (int nt = 0; nt < 5; ++nt)
                    acc[mt][nt] = __builtin_amdgcn_mfma_f32_16x16x32_bf16(
                        af[mt], bf[nt], acc[mt][nt], 0, 0, 0);
        }
        __builtin_amdgcn_s_setprio(0);
        __builtin_amdgcn_sched_barrier(0);
        asm volatile("s_barrier" ::: "memory");        // sAb[p]/sBb[p] free to restage
    }

    // ---- epilogue 1: transpose via LDS (aliases dead sA/sB), coalesced column stores
#pragma unroll
    for (int mt = 0; mt < 4; ++mt) {
#pragma unroll
        for (int nt = 0; nt < 5; ++nt) {
            int col = cbase + nt * 16 + m16;
            int row = mrow + mt * 16 + quad * 4;
            f32x4 v = acc[mt][nt];
            unsigned lo = (unsigned)f2bf(v.x) | ((unsigned)f2bf(v.y) << 16);
            unsigned hi = (unsigned)f2bf(v.z) | ((unsigned)f2bf(v.w) << 16);
            uint2 pk; pk.x = lo; pk.y = hi;
            *(uint2*)(smem + col * 272 + row * 2) = pk;   // col stride 136 ushorts
        }
    }
    __syncthreads();
#pragma unroll
    for (int it = 0; it < 20; ++it) {                  // 320 cols = 20 x (16 cols x 32 ln)
        int col = it * 16 + (tid >> 5);
        int l32 = tid & 31;
        uint2 v = *(const uint2*)(smem + col * 272 + l32 * 8);
        *(uint2*)(hbuf + (size_t)col * SROW + m0 + l32 * 4) = v;  // 256B runs
    }

    // ---- epilogue 2: BN statistics (pad/invalid rows are exact zeros) ----
    float s[5], ss[5];
#pragma unroll
    for (int nt = 0; nt < 5; ++nt) {
        float a = 0.f, b = 0.f;
#pragma unroll
        for (int mt = 0; mt < 4; ++mt) {
            f32x4 v = acc[mt][nt];
            a += v.x + v.y + v.z + v.w;
            b += v.x * v.x + v.y * v.y + v.z * v.z + v.w * v.w;
        }
        s[nt] = a; ss[nt] = b;
        s[nt] += __shfl_xor(s[nt], 16); s[nt] += __shfl_xor(s[nt], 32);
        ss[nt] += __shfl_xor(ss[nt], 16); ss[nt] += __shfl_xor(ss[nt], 32);
    }
    if (quad == 0) {   // SRED region (88064+) does not alias transpose data (<87040)
#pragma unroll
        for (int nt = 0; nt < 5; ++nt) {
            float* p = (float*)(smem + SRED_OFF + (w * 80 + nt * 16 + m16) * 8);
            p[0] = s[nt]; p[1] = ss[nt];
        }
    }
    __syncthreads();
    if (tid < NCOL) {
        int c = tid;
        int qq = c / 80, lc = c - qq * 80;   // waves qq (rows 0-63) and qq+4 (64-127)
        const float* p0 = (const float*)(smem + SRED_OFF + (qq * 80 + lc) * 8);
        const float* p1 = (const float*)(smem + SRED_OFF + ((qq + 4) * 80 + lc) * 8);
        atomicAdd(&stats[c], p0[0] + p1[0]);
        atomicAdd(&stats[NCOL + c], p0[1] + p1[1]);
    }
}

// ------- pass 2: BN + ReLU + 1x1 conv, per-HEAD grid (5x parallelism, 64 loads/thread)
__global__ __launch_bounds__(256)
void head_kernel(const unsigned short* __restrict__ hbuf,
                 const float* __restrict__ stats,
                 const float* __restrict__ gamma, const float* __restrict__ beta,
                 const float* __restrict__ W1_0, const float* __restrict__ W1_1,
                 const float* __restrict__ W1_2, const float* __restrict__ W1_3,
                 const float* __restrict__ W1_4,
                 const float* __restrict__ b1_0, const float* __restrict__ b1_1,
                 const float* __restrict__ b1_2, const float* __restrict__ b1_3,
                 const float* __restrict__ b1_4,
                 float* __restrict__ out) {
    __shared__ float sScale[64], sShift[64], sW1[192], sB1[3];
    int h = blockIdx.y;
    const float* W1; const float* b1; int oc; size_t obase;
    if (h == 0)      { W1 = W1_0; b1 = b1_0; oc = 3; obase = 0; }
    else if (h == 1) { W1 = W1_1; b1 = b1_1; oc = 2; obase = 450000; }
    else if (h == 2) { W1 = W1_2; b1 = b1_2; oc = 1; obase = 750000; }
    else if (h == 3) { W1 = W1_3; b1 = b1_3; oc = 3; obase = 900000; }
    else             { W1 = W1_4; b1 = b1_4; oc = 2; obase = 1350000; }

    int tid = threadIdx.x;
    if (tid < 64) {
        int c = h * 64 + tid;
        float mean = stats[c] * (1.f / (float)NVOX);
        float var = stats[NCOL + c] * (1.f / (float)NVOX) - mean * mean;
        float inv = rsqrtf(var + 1e-5f);
        float sc = inv * gamma[c];
        sScale[tid] = sc;
        sShift[tid] = beta[c] - mean * sc;
    }
    for (int i = tid; i < 192; i += 256) {
        int cc = i / 3, jj = i - cc * 3;
        sW1[i] = (jj < oc) ? W1[cc * oc + jj] : 0.f;
    }
    if (tid == 0) {
        sB1[0] = b1[0];
        sB1[1] = (oc >= 2) ? b1[1] : 0.f;
        sB1[2] = (oc >= 3) ? b1[2] : 0.f;
    }
    __syncthreads();

    int n = (blockIdx.x * 256 + tid) * 4;    // 4 rows per thread (NVOX % 4 == 0)
    if (n >= NVOX) return;
    const unsigned short* hp = hbuf + (size_t)(h * 64) * SROW + n;
    float x[4][3];
#pragma unroll
    for (int rr = 0; rr < 4; ++rr) { x[rr][0] = sB1[0]; x[rr][1] = sB1[1]; x[rr][2] = sB1[2]; }
#pragma unroll 8
    for (int cc = 0; cc < 64; ++cc) {
        uint2 raw = *(const uint2*)(hp + (size_t)cc * SROW);   // rows n..n+3, bf16
        float sc = sScale[cc], sh = sShift[cc];
        float w0 = sW1[cc * 3 + 0], w1 = sW1[cc * 3 + 1], w2 = sW1[cc * 3 + 2];
        float v0 = __builtin_bit_cast(float, raw.x << 16);
        float v1 = __builtin_bit_cast(float, raw.x & 0xffff0000u);
        float v2 = __builtin_bit_cast(float, raw.y << 16);
        float v3 = __builtin_bit_cast(float, raw.y & 0xffff0000u);
        v0 = fmaxf(v0 * sc + sh, 0.f); v1 = fmaxf(v1 * sc + sh, 0.f);
        v2 = fmaxf(v2 * sc + sh, 0.f); v3 = fmaxf(v3 * sc + sh, 0.f);
        x[0][0] += v0 * w0; x[0][1] += v0 * w1; x[0][2] += v0 * w2;
        x[1][0] += v1 * w0; x[1][1] += v1 * w1; x[1][2] += v1 * w2;
        x[2][0] += v2 * w0; x[2][1] += v2 * w1; x[2][2] += v2 * w2;
        x[3][0] += v3 * w0; x[3][1] += v3 * w1; x[3][2] += v3 * w2;
    }
#pragma unroll
    for (int rr = 0; rr < 4; ++rr) {
        float* op = out + obase + (size_t)(n + rr) * oc;
        op[0] = x[rr][0];                 // oc is block-uniform; x indices all static
        if (oc >= 2) op[1] = x[rr][1];
        if (oc >= 3) op[2] = x[rr][2];
    }
}

extern "C" void kernel_launch(void* const* d_in, const int* in_sizes, int n_in,
                              void* d_out, int out_size, void* d_ws, size_t ws_size,
                              hipStream_t stream) {
    const float* features = (const float*)d_in[0];
    const int* nbr        = (const int*)d_in[1];
    const float* w3       = (const float*)d_in[2];
    const float* gamma    = (const float*)d_in[3];
    const float* beta     = (const float*)d_in[4];
    const float* W1_0 = (const float*)d_in[5];  const float* b1_0 = (const float*)d_in[6];
    const float* W1_1 = (const float*)d_in[7];  const float* b1_1 = (const float*)d_in[8];
    const float* W1_2 = (const float*)d_in[9];  const float* b1_2 = (const float*)d_in[10];
    const float* W1_3 = (const float*)d_in[11]; const float* b1_3 = (const float*)d_in[12];
    const float* W1_4 = (const float*)d_in[13]; const float* b1_4 = (const float*)d_in[14];
    float* out = (float*)d_out;

    char* ws = (char*)d_ws;
    unsigned short* featB = (unsigned short*)ws;               // (150000+1)*64 bf16
    unsigned short* Bt2   = (unsigned short*)(ws + 19200128);  // 5*9*8*512 bf16
    float* stats          = (float*)(ws + 19568768);           // 640 f32
    unsigned short* hbuf  = (unsigned short*)(ws + 19571328);  // 320*150016 bf16

    prep_feat<<<(NVOX * 8 + 8 + 255) / 256, 256, 0, stream>>>(features, featB);
    prep_w3<<<184320 / 256, 256, 0, stream>>>(w3, Bt2, stats);
    gemm_kernel<<<MTILES, 512, 0, stream>>>(featB, Bt2, nbr, hbuf, stats);
    head_kernel<<<dim3(147, 5), 256, 0, stream>>>(hbuf, stats, gamma, beta,
        W1_0, W1_1, W1_2, W1_3, W1_4, b1_0, b1_1, b1_2, b1_3, b1_4, out);
}